// Round 4
// baseline (1097.220 us; speedup 1.0000x reference)
//
#include <hip/hip_runtime.h>

// ContextualCouplingTSA: LN -> split x1/x2 -> QKV(x1) -> conv-bias attn ->
// softmax (attn is an OUTPUT) -> ctx -> scale/shift -> y2 -> [x1|y2]@Wo.
// Shapes: B=4, L=2048, DM=1024, DC=512, H=8, DH=64. All inputs fp32.
// d_out = out (8192x1024 f32) ++ attn (4x8x2048x2048 f32).
// Softmax runs in exp2 domain (v_exp_f32 is base-2): sal is pre-scaled by
// alpha*log2e in conv_k, score scale is 0.125*log2e, stats store log2-max.
// MFMA via __builtin_amdgcn_mfma_f32_16x16x32_bf16 (compiler-managed
// hazards; inline-asm MFMA lacked post-MFMA VALU wait states -> NaN).

#define BB 4
#define LL 2048
#define DM 1024
#define DC 512
#define NH 8
#define DH 64
#define LOG2E 1.4426950408889634f
#define SCL (0.125f * LOG2E)

typedef __attribute__((ext_vector_type(8))) short short8;
typedef __attribute__((ext_vector_type(8))) __bf16 bf16x8;
typedef __attribute__((ext_vector_type(4))) float f32x4;

#define DEV static __device__ __forceinline__

#if __has_builtin(__builtin_amdgcn_exp2f)
#define EXP2F(x) __builtin_amdgcn_exp2f(x)
#else
#define EXP2F(x) exp2f(x)
#endif

DEV void MFMA(f32x4& c, short8 a, short8 b) {
  c = __builtin_amdgcn_mfma_f32_16x16x32_bf16(
      __builtin_bit_cast(bf16x8, a), __builtin_bit_cast(bf16x8, b), c, 0, 0, 0);
}

DEV unsigned short f2b(float f) {
  union { float f; unsigned u; } v; v.f = f;
  unsigned r = v.u + 0x7FFFu + ((v.u >> 16) & 1u);
  return (unsigned short)(r >> 16);
}
DEV float b2f(unsigned short u) {
  union { unsigned u; float f; } v; v.u = ((unsigned)u) << 16; return v.f;
}

typedef const __attribute__((address_space(1))) void GVOID;
typedef __attribute__((address_space(3))) void LVOID;
#define GLDS16(gp, lp) __builtin_amdgcn_global_load_lds((GVOID*)(gp), (LVOID*)(lp), 16, 0, 0)

// ---------------- fp32 -> bf16 convert (weights) ----------------
__global__ void cvt_k(const float* __restrict__ src, unsigned short* __restrict__ dst, int n4) {
  int i = blockIdx.x * blockDim.x + threadIdx.x;
  if (i < n4) {
    float4 v = *(const float4*)&src[(size_t)i * 4];
    ushort4 o; o.x = f2b(v.x); o.y = f2b(v.y); o.z = f2b(v.z); o.w = f2b(v.w);
    *(ushort4*)&dst[(size_t)i * 4] = o;
  }
}

// ---------------- LayerNorm ----------------
__global__ __launch_bounds__(256) void ln_k(const float* __restrict__ src,
    const float* __restrict__ g, const float* __restrict__ be,
    unsigned short* __restrict__ xcat, float* __restrict__ x2f) {
  int row = blockIdx.x, tid = threadIdx.x;
  const float* s = src + (size_t)row * DM;
  float4 v = *(const float4*)&s[tid * 4];
  float sum = v.x + v.y + v.z + v.w;
  float sq  = v.x * v.x + v.y * v.y + v.z * v.z + v.w * v.w;
#pragma unroll
  for (int o = 32; o > 0; o >>= 1) { sum += __shfl_down(sum, o); sq += __shfl_down(sq, o); }
  __shared__ float red[8];
  __shared__ float mu_s, rs_s;
  int wave = tid >> 6, lane = tid & 63;
  if (lane == 0) { red[wave] = sum; red[4 + wave] = sq; }
  __syncthreads();
  if (tid == 0) {
    float S = red[0] + red[1] + red[2] + red[3];
    float Q = red[4] + red[5] + red[6] + red[7];
    float mu = S * (1.f / DM);
    float var = Q * (1.f / DM) - mu * mu;
    mu_s = mu; rs_s = rsqrtf(var + 1e-5f);
  }
  __syncthreads();
  float mu = mu_s, rs = rs_s;
  float4 gv = *(const float4*)&g[tid * 4];
  float4 bv = *(const float4*)&be[tid * 4];
  float y0 = (v.x - mu) * rs * gv.x + bv.x;
  float y1 = (v.y - mu) * rs * gv.y + bv.y;
  float y2 = (v.z - mu) * rs * gv.z + bv.z;
  float y3 = (v.w - mu) * rs * gv.w + bv.w;
  int c = tid * 4;
  if (c < DC) {
    ushort4 o; o.x = f2b(y0); o.y = f2b(y1); o.z = f2b(y2); o.w = f2b(y3);
    *(ushort4*)&xcat[(size_t)row * DM + c] = o;
  } else {
    float4 o; o.x = y0; o.y = y1; o.z = y2; o.w = y3;
    *(float4*)&x2f[(size_t)row * DC + (c - DC)] = o;
  }
}

// ---------------- bf16 MFMA GEMM: out = A @ W^T + bias ----------------
// A: [M][lda] bf16. W: [N][K] bf16 (row-major, ld=K). 128x128 tile, BK=32.
// MODE 0: out bf16, scatter [b,h,l,d]   (Q,K)
// MODE 1: out bf16, scatter [b,h,d,l]   (V transposed)
// MODE 2: out f32, row-major [M][N]     (ls/sh/final)
template <int MODE>
__global__ __launch_bounds__(256) void gemm_k(const unsigned short* __restrict__ A, int lda,
    const unsigned short* __restrict__ W, const float* __restrict__ bias,
    void* __restrict__ outp, int N, int K) {
  __shared__ alignas(16) unsigned short lA[128 * 32];
  __shared__ alignas(16) unsigned short lB[128 * 32];
  int tid = threadIdx.x, lane = tid & 63, wave = tid >> 6;
  int bm = blockIdx.y * 128, bn = blockIdx.x * 128;
  int wm = (wave >> 1) * 64, wn = (wave & 1) * 64;
  int l15 = lane & 15, lg = lane >> 4;
  f32x4 acc[4][4];
#pragma unroll
  for (int i = 0; i < 4; i++)
#pragma unroll
    for (int j = 0; j < 4; j++) acc[i][j] = f32x4{0.f, 0.f, 0.f, 0.f};

  for (int k0 = 0; k0 < K; k0 += 32) {
#pragma unroll
    for (int it = 0; it < 2; it++) {
      int ch = it * 256 + tid;          // 512 chunks of 16B per tile
      int r = ch >> 2, c8 = (ch & 3) * 8;
      GLDS16(A + (size_t)(bm + r) * lda + (k0 + c8), &lA[ch * 8]);
      GLDS16(W + (size_t)(bn + r) * K + (k0 + c8), &lB[ch * 8]);
    }
    __syncthreads();
    short8 af[4], bf[4];
#pragma unroll
    for (int f = 0; f < 4; f++) {
      af[f] = *(const short8*)&lA[(wm + f * 16 + l15) * 32 + lg * 8];
      bf[f] = *(const short8*)&lB[(wn + f * 16 + l15) * 32 + lg * 8];
    }
#pragma unroll
    for (int fm = 0; fm < 4; fm++)
#pragma unroll
      for (int fn = 0; fn < 4; fn++) MFMA(acc[fm][fn], af[fm], bf[fn]);
    __syncthreads();
  }

#pragma unroll
  for (int fm = 0; fm < 4; fm++) {
#pragma unroll
    for (int fn = 0; fn < 4; fn++) {
      int col = bn + wn + fn * 16 + l15;
      float bv = bias[col];
#pragma unroll
      for (int r = 0; r < 4; r++) {
        int row = bm + wm + fm * 16 + lg * 4 + r;
        float v = acc[fm][fn][r] + bv;
        if (MODE == 0) {
          ((unsigned short*)outp)[((size_t)(((row >> 11) * NH + (col >> 6)) * LL + (row & 2047))) * DH + (col & 63)] = f2b(v);
        } else if (MODE == 1) {
          ((unsigned short*)outp)[((size_t)(((row >> 11) * NH + (col >> 6)) * DH + (col & 63))) * LL + (row & 2047)] = f2b(v);
        } else {
          ((float*)outp)[(size_t)row * N + col] = v;
        }
      }
    }
  }
}

// ------- conv over channels -> sal[b,h,l] = alpha*log2e*(conv + cb) -------
__global__ __launch_bounds__(256) void conv_k(const unsigned short* __restrict__ xcat,
    const float* __restrict__ cw, const float* __restrict__ cb,
    const float* __restrict__ alphap, float* __restrict__ sal) {
  __shared__ alignas(16) unsigned short lx[34][516];  // rows l0-1 .. l0+32, +4 pad
  int b = blockIdx.y, l0 = blockIdx.x * 32, tid = threadIdx.x;
  for (int i = tid; i < 34 * 128; i += 256) {
    int r = i >> 7, c4 = (i & 127) * 4;
    int l = l0 - 1 + r;
    ushort4 v; v.x = v.y = v.z = v.w = 0;
    if (l >= 0 && l < LL) v = *(const ushort4*)&xcat[((size_t)b * LL + l) * DM + c4];
    *(ushort4*)&lx[r][c4] = v;
  }
  __syncthreads();
  int h = tid >> 5, li = tid & 31;
  int l = l0 + li;
  const float* w = cw + (size_t)h * DC * 3;
  float acc = cb[h];
  for (int c = 0; c < DC; c += 4) {
#pragma unroll
    for (int k = 0; k < 3; k++) {
      ushort4 xv = *(const ushort4*)&lx[li + k][c];
      acc += b2f(xv.x) * w[(c + 0) * 3 + k] + b2f(xv.y) * w[(c + 1) * 3 + k] +
             b2f(xv.z) * w[(c + 2) * 3 + k] + b2f(xv.w) * w[(c + 3) * 3 + k];
    }
  }
  sal[((size_t)b * NH + h) * LL + l] = acc * (alphap[0] * LOG2E);
}

// ---------------- attention pass A: per-row (log2-max, sumexp2) ----------------
// Per-lane online partials (lane owns keys == l15 mod 16); ONE butterfly at end.
__global__ __launch_bounds__(256) void attn_pa(const unsigned short* __restrict__ Qb,
    const unsigned short* __restrict__ Kb, const float* __restrict__ sal,
    float* __restrict__ stats) {
  int bh = blockIdx.y, qb = blockIdx.x * 64;
  int tid = threadIdx.x, lane = tid & 63, wave = tid >> 6;
  int l15 = lane & 15, lg = lane >> 4;
  const unsigned short* Qh = Qb + (size_t)bh * LL * DH;
  const unsigned short* Kh = Kb + (size_t)bh * LL * DH;
  const float* sl = sal + (size_t)bh * LL;
  int q = qb + wave * 16 + l15;
  short8 qf0 = *(const short8*)&Qh[q * DH + lg * 8];
  short8 qf1 = *(const short8*)&Qh[q * DH + 32 + lg * 8];
  float m[4], s[4];
#pragma unroll
  for (int r = 0; r < 4; r++) { m[r] = -1e30f; s[r] = 0.f; }
  for (int kt = 0; kt < LL; kt += 64) {
    float sc[4][4];
#pragma unroll
    for (int fn = 0; fn < 4; fn++) {
      int key = kt + fn * 16 + l15;
      short8 k0 = *(const short8*)&Kh[key * DH + lg * 8];
      short8 k1 = *(const short8*)&Kh[key * DH + 32 + lg * 8];
      f32x4 c = {0.f, 0.f, 0.f, 0.f};
      MFMA(c, qf0, k0);
      MFMA(c, qf1, k1);
      float sv = sl[key];
#pragma unroll
      for (int r = 0; r < 4; r++) sc[fn][r] = c[r] * SCL + sv;
    }
#pragma unroll
    for (int r = 0; r < 4; r++) {
      float t = fmaxf(fmaxf(sc[0][r], sc[1][r]), fmaxf(sc[2][r], sc[3][r]));
      float nm = fmaxf(m[r], t);
      float e = EXP2F(sc[0][r] - nm) + EXP2F(sc[1][r] - nm) +
                EXP2F(sc[2][r] - nm) + EXP2F(sc[3][r] - nm);
      s[r] = s[r] * EXP2F(m[r] - nm) + e;
      m[r] = nm;
    }
  }
  // combine the 16 per-lane partials of each row (butterfly over l15 bits)
#pragma unroll
  for (int r = 0; r < 4; r++) {
    float m2 = m[r], s2 = s[r];
#pragma unroll
    for (int o = 1; o < 16; o <<= 1) {
      float mo = __shfl_xor(m2, o);
      float so = __shfl_xor(s2, o);
      float nm = fmaxf(m2, mo);
      s2 = s2 * EXP2F(m2 - nm) + so * EXP2F(mo - nm);
      m2 = nm;
    }
    m[r] = m2; s[r] = s2;
  }
  if (l15 == 0) {
#pragma unroll
    for (int r = 0; r < 4; r++) {
      size_t R = (size_t)bh * LL + qb + wave * 16 + lg * 4 + r;
      stats[R * 2] = m[r];
      stats[R * 2 + 1] = s[r];
    }
  }
}

// ---------------- attention pass B: write attn, accumulate ctx ----------------
// P staged in f32 LDS (wave-private slice); barriers around the tile use.
// attn stored as coalesced dwordx4 (1KB per instruction per wave).
__global__ __launch_bounds__(256) void attn_pb(const unsigned short* __restrict__ Qb,
    const unsigned short* __restrict__ Kb, const unsigned short* __restrict__ Vt,
    const float* __restrict__ sal, const float* __restrict__ stats,
    unsigned short* __restrict__ ctxb, float* __restrict__ attn) {
  __shared__ alignas(16) float plf[4][16][68];   // [wave][qrow16][key64+pad]
  int bh = blockIdx.y, qb = blockIdx.x * 64;
  int tid = threadIdx.x, lane = tid & 63, wave = tid >> 6;
  int l15 = lane & 15, lg = lane >> 4;
  const unsigned short* Qh = Qb + (size_t)bh * LL * DH;
  const unsigned short* Kh = Kb + (size_t)bh * LL * DH;
  const unsigned short* Vh = Vt + (size_t)bh * DH * LL;
  const float* sl = sal + (size_t)bh * LL;
  int q = qb + wave * 16 + l15;
  short8 qf0 = *(const short8*)&Qh[q * DH + lg * 8];
  short8 qf1 = *(const short8*)&Qh[q * DH + 32 + lg * 8];
  float mr[4], si[4];
#pragma unroll
  for (int r = 0; r < 4; r++) {
    size_t R = (size_t)bh * LL + qb + wave * 16 + lg * 4 + r;
    mr[r] = stats[R * 2];
    si[r] = 1.f / stats[R * 2 + 1];
  }
  f32x4 cacc[4];
#pragma unroll
  for (int fd = 0; fd < 4; fd++) cacc[fd] = f32x4{0.f, 0.f, 0.f, 0.f};
  float* ah = attn + (size_t)bh * LL * LL;
  for (int kt = 0; kt < LL; kt += 64) {
#pragma unroll
    for (int fn = 0; fn < 4; fn++) {
      int key = kt + fn * 16 + l15;
      short8 k0 = *(const short8*)&Kh[key * DH + lg * 8];
      short8 k1 = *(const short8*)&Kh[key * DH + 32 + lg * 8];
      f32x4 c = {0.f, 0.f, 0.f, 0.f};
      MFMA(c, qf0, k0);
      MFMA(c, qf1, k1);
      float sv = sl[key];
#pragma unroll
      for (int r = 0; r < 4; r++) {
        float p = EXP2F(c[r] * SCL + sv - mr[r]) * si[r];
        plf[wave][lg * 4 + r][fn * 16 + l15] = p;
      }
    }
    __syncthreads();
    // PV: build bf16 P-fragments from the wave's own LDS tile
    {
      float4 a0 = *(const float4*)&plf[wave][l15][lg * 8];
      float4 a1 = *(const float4*)&plf[wave][l15][lg * 8 + 4];
      float4 b0 = *(const float4*)&plf[wave][l15][32 + lg * 8];
      float4 b1 = *(const float4*)&plf[wave][l15][32 + lg * 8 + 4];
      short8 pf0, pf1;
      pf0[0] = f2b(a0.x); pf0[1] = f2b(a0.y); pf0[2] = f2b(a0.z); pf0[3] = f2b(a0.w);
      pf0[4] = f2b(a1.x); pf0[5] = f2b(a1.y); pf0[6] = f2b(a1.z); pf0[7] = f2b(a1.w);
      pf1[0] = f2b(b0.x); pf1[1] = f2b(b0.y); pf1[2] = f2b(b0.z); pf1[3] = f2b(b0.w);
      pf1[4] = f2b(b1.x); pf1[5] = f2b(b1.y); pf1[6] = f2b(b1.z); pf1[7] = f2b(b1.w);
#pragma unroll
      for (int fd = 0; fd < 4; fd++) {
        int d = fd * 16 + l15;
        short8 v0 = *(const short8*)&Vh[(size_t)d * LL + kt + lg * 8];
        short8 v1 = *(const short8*)&Vh[(size_t)d * LL + kt + 32 + lg * 8];
        MFMA(cacc[fd], pf0, v0);
        MFMA(cacc[fd], pf1, v1);
      }
    }
    // coalesced attn store: 4 rows x 64 cols per instruction
#pragma unroll
    for (int it = 0; it < 4; it++) {
      int row = it * 4 + lg;
      float4 v = *(const float4*)&plf[wave][row][l15 * 4];
      *(float4*)&ah[(size_t)(qb + wave * 16 + row) * LL + kt + l15 * 4] = v;
    }
    __syncthreads();
  }
  int b = bh >> 3, h = bh & 7;
#pragma unroll
  for (int fd = 0; fd < 4; fd++) {
    int d = fd * 16 + l15;
#pragma unroll
    for (int r = 0; r < 4; r++) {
      int row = qb + wave * 16 + lg * 4 + r;
      ctxb[((size_t)b * LL + row) * DC + h * DH + d] = f2b(cacc[fd][r]);
    }
  }
}

// ---------------- y2 = exp(clip(ls)) * x2 + sh -> xcat[:, 512:] ----------------
__global__ __launch_bounds__(256) void y2_k(const float* __restrict__ ls,
    const float* __restrict__ sh, const float* __restrict__ x2f,
    unsigned short* __restrict__ xcat) {
  int i = blockIdx.x * blockDim.x + threadIdx.x;  // over 8192*512/4
  float4 a = *(const float4*)&ls[(size_t)i * 4];
  float4 t = *(const float4*)&sh[(size_t)i * 4];
  float4 x = *(const float4*)&x2f[(size_t)i * 4];
  float y0 = __expf(fminf(fmaxf(a.x, -2.f), 2.f)) * x.x + t.x;
  float y1 = __expf(fminf(fmaxf(a.y, -2.f), 2.f)) * x.y + t.y;
  float y2 = __expf(fminf(fmaxf(a.z, -2.f), 2.f)) * x.z + t.z;
  float y3 = __expf(fminf(fmaxf(a.w, -2.f), 2.f)) * x.w + t.w;
  int row = (i * 4) >> 9;
  int c = (i * 4) & 511;
  ushort4 o; o.x = f2b(y0); o.y = f2b(y1); o.z = f2b(y2); o.w = f2b(y3);
  *(ushort4*)&xcat[(size_t)row * DM + DC + c] = o;
}

extern "C" void kernel_launch(void* const* d_in, const int* in_sizes, int n_in,
                              void* d_out, int out_size, void* d_ws, size_t ws_size,
                              hipStream_t stream) {
  const float* src  = (const float*)d_in[0];
  const float* ln_g = (const float*)d_in[1];
  const float* ln_b = (const float*)d_in[2];
  const float* Wq   = (const float*)d_in[3];
  const float* bq   = (const float*)d_in[4];
  const float* Wk   = (const float*)d_in[5];
  const float* bk   = (const float*)d_in[6];
  const float* Wv   = (const float*)d_in[7];
  const float* bv   = (const float*)d_in[8];
  const float* cw   = (const float*)d_in[9];
  const float* cb   = (const float*)d_in[10];
  const float* alpha= (const float*)d_in[11];
  const float* Wsp  = (const float*)d_in[12];
  const float* bs   = (const float*)d_in[13];
  const float* Wtp  = (const float*)d_in[14];
  const float* bt   = (const float*)d_in[15];
  const float* Wo   = (const float*)d_in[16];
  const float* bo   = (const float*)d_in[17];

  char* ws = (char*)d_ws;
  size_t off = 0;
  auto alloc = [&](size_t bytes) -> void* {
    void* p = ws + off;
    off += (bytes + 255) & ~(size_t)255;
    return p;
  };
  unsigned short* xcat = (unsigned short*)alloc((size_t)8192 * 1024 * 2); // [x1b | y2b]
  float*          x2f  = (float*)alloc((size_t)8192 * 512 * 4);
  unsigned short* Wqb  = (unsigned short*)alloc((size_t)512 * 512 * 2);
  unsigned short* Wkb  = (unsigned short*)alloc((size_t)512 * 512 * 2);
  unsigned short* Wvb  = (unsigned short*)alloc((size_t)512 * 512 * 2);
  unsigned short* Wsb  = (unsigned short*)alloc((size_t)512 * 512 * 2);
  unsigned short* Wtb  = (unsigned short*)alloc((size_t)512 * 512 * 2);
  unsigned short* Wob  = (unsigned short*)alloc((size_t)1024 * 1024 * 2);
  unsigned short* Qbuf = (unsigned short*)alloc((size_t)8192 * 512 * 2);  // [b,h,l,d]
  unsigned short* Kbuf = (unsigned short*)alloc((size_t)8192 * 512 * 2);  // [b,h,l,d]
  unsigned short* Vt   = (unsigned short*)alloc((size_t)8192 * 512 * 2);  // [b,h,d,l]
  unsigned short* ctxb = (unsigned short*)alloc((size_t)8192 * 512 * 2);  // [b,l,dc]
  float*          sal  = (float*)alloc((size_t)BB * NH * LL * 4);
  float*          stats= (float*)alloc((size_t)BB * NH * LL * 2 * 4);

  float* outF = (float*)d_out;
  float* attn = outF + (size_t)8192 * 1024;
  // ls/shift scratch inside d_out's `out` region (8192*1024 floats, written last)
  float* lsb = outF;                       // 8192*512
  float* shb = outF + (size_t)8192 * 512;  // 8192*512

  // weights -> bf16
  cvt_k<<<256, 256, 0, stream>>>(Wq, Wqb, 65536);
  cvt_k<<<256, 256, 0, stream>>>(Wk, Wkb, 65536);
  cvt_k<<<256, 256, 0, stream>>>(Wv, Wvb, 65536);
  cvt_k<<<256, 256, 0, stream>>>(Wsp, Wsb, 65536);
  cvt_k<<<256, 256, 0, stream>>>(Wtp, Wtb, 65536);
  cvt_k<<<1024, 256, 0, stream>>>(Wo, Wob, 262144);

  ln_k<<<8192, 256, 0, stream>>>(src, ln_g, ln_b, xcat, x2f);

  gemm_k<0><<<dim3(4, 64), 256, 0, stream>>>(xcat, DM, Wqb, bq, Qbuf, 512, 512);
  gemm_k<0><<<dim3(4, 64), 256, 0, stream>>>(xcat, DM, Wkb, bk, Kbuf, 512, 512);
  gemm_k<1><<<dim3(4, 64), 256, 0, stream>>>(xcat, DM, Wvb, bv, Vt, 512, 512);

  conv_k<<<dim3(64, 4), 256, 0, stream>>>(xcat, cw, cb, alpha, sal);

  attn_pa<<<dim3(32, 32), 256, 0, stream>>>(Qbuf, Kbuf, sal, stats);
  attn_pb<<<dim3(32, 32), 256, 0, stream>>>(Qbuf, Kbuf, Vt, sal, stats, ctxb, attn);

  gemm_k<2><<<dim3(4, 64), 256, 0, stream>>>(ctxb, DC, Wsb, bs, lsb, 512, 512);
  gemm_k<2><<<dim3(4, 64), 256, 0, stream>>>(ctxb, DC, Wtb, bt, shb, 512, 512);

  y2_k<<<4096, 256, 0, stream>>>(lsb, shb, x2f, xcat);

  gemm_k<2><<<dim3(8, 64), 256, 0, stream>>>(xcat, DM, Wob, bo, outF, 1024, 1024);
}